// Round 5
// baseline (381.509 us; speedup 1.0000x reference)
//
#include <hip/hip_runtime.h>

#define DIM 96
#define CHUNKS 24   // DIM / 4 float4 chunks per node row
#define GBLK 192    // 8 nodes per block in gather
#define R_TILE 32   // rows per block in fused GEMM
#define SCAN_CHUNK 1024  // elements per block in phase-1 scan

// ---------------------------------------------------------------------------
__global__ void deg_kernel(const int* __restrict__ row, int E, int* __restrict__ degi) {
    int e = blockIdx.x * blockDim.x + threadIdx.x;
    if (e < E) atomicAdd(&degi[row[e]], 1);
}

__global__ void dinv_kernel(const int* __restrict__ degi, float* __restrict__ dinv, int N) {
    int i = blockIdx.x * blockDim.x + threadIdx.x;
    if (i < N) {
        int d = degi[i];
        dinv[i] = (d > 0) ? rsqrtf((float)d) : 0.0f;
    }
}

// ---- multi-block exclusive scan of degi -> offsets ----
__global__ __launch_bounds__(256) void scan_blocks_kernel(
        const int* __restrict__ degi, int* __restrict__ offsets,
        int* __restrict__ blocksums, int N) {
    __shared__ int s[256];
    const int t = threadIdx.x;
    const int base = blockIdx.x * SCAN_CHUNK + t * 4;
    int v0 = 0, v1 = 0, v2 = 0, v3 = 0;
    if (base + 3 < N) {
        const int4 q = *reinterpret_cast<const int4*>(degi + base);
        v0 = q.x; v1 = q.y; v2 = q.z; v3 = q.w;
    } else {
        if (base + 0 < N) v0 = degi[base + 0];
        if (base + 1 < N) v1 = degi[base + 1];
        if (base + 2 < N) v2 = degi[base + 2];
        if (base + 3 < N) v3 = degi[base + 3];
    }
    const int mysum = v0 + v1 + v2 + v3;
    s[t] = mysum;
    __syncthreads();
    for (int off = 1; off < 256; off <<= 1) {
        int x = (t >= off) ? s[t - off] : 0;
        __syncthreads();
        s[t] += x;
        __syncthreads();
    }
    int run = s[t] - mysum;
    if (t == 255) blocksums[blockIdx.x] = s[255];
    if (base + 0 < N) offsets[base + 0] = run;  run += v0;
    if (base + 1 < N) offsets[base + 1] = run;  run += v1;
    if (base + 2 < N) offsets[base + 2] = run;  run += v2;
    if (base + 3 < N) offsets[base + 3] = run;
}

__global__ __launch_bounds__(256) void scan_sums_kernel(int* __restrict__ blocksums, int nb) {
    __shared__ int s[256];
    const int t = threadIdx.x;
    const int v = (t < nb) ? blocksums[t] : 0;
    s[t] = v;
    __syncthreads();
    for (int off = 1; off < 256; off <<= 1) {
        int x = (t >= off) ? s[t - off] : 0;
        __syncthreads();
        s[t] += x;
        __syncthreads();
    }
    if (t < nb) blocksums[t] = s[t] - v;
}

__global__ __launch_bounds__(256) void scan_add_kernel(
        int* __restrict__ offsets, const int* __restrict__ blocksums, int N, int E) {
    const int i = blockIdx.x * blockDim.x + threadIdx.x;
    if (i < N) offsets[i] += blocksums[i >> 10];  // SCAN_CHUNK == 1024
    if (i == 0) offsets[N] = E;
}

__global__ void build_csr_kernel(const int* __restrict__ row, const int* __restrict__ col,
                                 const float* __restrict__ dinv, const int* __restrict__ offsets,
                                 int* __restrict__ fill, int* __restrict__ colsorted,
                                 float* __restrict__ wsorted, int E) {
    int e = blockIdx.x * blockDim.x + threadIdx.x;
    if (e >= E) return;
    int r = row[e];
    int p = offsets[r] + atomicAdd(&fill[r], 1);
    int c = col[e];
    colsorted[p] = c;
    wsorted[p] = dinv[c];
}

// dst[i][:] = -scale*dinv[i]*sum_e w[e]*h[col[e]][:] (- prev[i][:])
// 4x unrolled: 4 independent row-gathers in flight per thread.
__global__ __launch_bounds__(GBLK) void gather_kernel(
        const int* __restrict__ offsets, const int* __restrict__ colsorted,
        const float* __restrict__ wsorted, const float* __restrict__ dinv,
        const float* __restrict__ h, const float* __restrict__ prev,
        float* __restrict__ dst, int N, float scale) {
    int tid = blockIdx.x * blockDim.x + threadIdx.x;
    int node = tid / CHUNKS;
    int c = tid % CHUNKS;
    if (node >= N) return;
    int s = offsets[node];
    int e = offsets[node + 1];
    const float* hc = h + c * 4;

    float4 a0 = make_float4(0.f, 0.f, 0.f, 0.f);
    float4 a1 = a0, a2 = a0, a3 = a0;
    int k = s;
    for (; k + 3 < e; k += 4) {
        int s0 = colsorted[k + 0], s1 = colsorted[k + 1];
        int s2 = colsorted[k + 2], s3 = colsorted[k + 3];
        float w0 = wsorted[k + 0], w1 = wsorted[k + 1];
        float w2 = wsorted[k + 2], w3 = wsorted[k + 3];
        const float4 v0 = *reinterpret_cast<const float4*>(hc + (size_t)s0 * DIM);
        const float4 v1 = *reinterpret_cast<const float4*>(hc + (size_t)s1 * DIM);
        const float4 v2 = *reinterpret_cast<const float4*>(hc + (size_t)s2 * DIM);
        const float4 v3 = *reinterpret_cast<const float4*>(hc + (size_t)s3 * DIM);
        a0.x = fmaf(w0, v0.x, a0.x); a0.y = fmaf(w0, v0.y, a0.y);
        a0.z = fmaf(w0, v0.z, a0.z); a0.w = fmaf(w0, v0.w, a0.w);
        a1.x = fmaf(w1, v1.x, a1.x); a1.y = fmaf(w1, v1.y, a1.y);
        a1.z = fmaf(w1, v1.z, a1.z); a1.w = fmaf(w1, v1.w, a1.w);
        a2.x = fmaf(w2, v2.x, a2.x); a2.y = fmaf(w2, v2.y, a2.y);
        a2.z = fmaf(w2, v2.z, a2.z); a2.w = fmaf(w2, v2.w, a2.w);
        a3.x = fmaf(w3, v3.x, a3.x); a3.y = fmaf(w3, v3.y, a3.y);
        a3.z = fmaf(w3, v3.z, a3.z); a3.w = fmaf(w3, v3.w, a3.w);
    }
    for (; k < e; ++k) {
        int s0 = colsorted[k];
        float w0 = wsorted[k];
        const float4 v0 = *reinterpret_cast<const float4*>(hc + (size_t)s0 * DIM);
        a0.x = fmaf(w0, v0.x, a0.x); a0.y = fmaf(w0, v0.y, a0.y);
        a0.z = fmaf(w0, v0.z, a0.z); a0.w = fmaf(w0, v0.w, a0.w);
    }
    float ax = (a0.x + a1.x) + (a2.x + a3.x);
    float ay = (a0.y + a1.y) + (a2.y + a3.y);
    float az = (a0.z + a1.z) + (a2.z + a3.z);
    float aw = (a0.w + a1.w) + (a2.w + a3.w);

    float m = -scale * dinv[node];
    float4 o = make_float4(m * ax, m * ay, m * az, m * aw);
    if (prev) {
        const float4 p = *reinterpret_cast<const float4*>(prev + (size_t)node * DIM + c * 4);
        o.x -= p.x; o.y -= p.y; o.z -= p.z; o.w -= p.w;
    }
    *reinterpret_cast<float4*>(dst + (size_t)node * DIM + c * 4) = o;
}

// Fused four-matrix GEMM: out = bias + A0@W0 + A1@W1 + A2@W2 + A3@W3
__global__ __launch_bounds__(192) void gemm4_kernel(
        const float* __restrict__ A0, const float* __restrict__ A1,
        const float* __restrict__ A2, const float* __restrict__ A3,
        const float* __restrict__ W,   // [4][DIM][DIM]
        const float* __restrict__ bias, float* __restrict__ out, int N) {
    __shared__ float sA[4][R_TILE][DIM + 1];
    const int tid = threadIdx.x;
    const int row0 = blockIdx.x * R_TILE;
    const float* As[4] = {A0, A1, A2, A3};

    for (int l = tid; l < 4 * R_TILE * CHUNKS; l += 192) {
        int m = l / (R_TILE * CHUNKS);
        int rem = l % (R_TILE * CHUNKS);
        int r = rem / CHUNKS;
        int cq = rem % CHUNKS;
        int g = row0 + r;
        float4 v = make_float4(0.f, 0.f, 0.f, 0.f);
        if (g < N) v = *reinterpret_cast<const float4*>(As[m] + (size_t)g * DIM + cq * 4);
        sA[m][r][cq * 4 + 0] = v.x; sA[m][r][cq * 4 + 1] = v.y;
        sA[m][r][cq * 4 + 2] = v.z; sA[m][r][cq * 4 + 3] = v.w;
    }
    __syncthreads();

    const int cq = tid % CHUNKS;
    const int r0 = tid / CHUNKS;
    float4 acc[4];
#pragma unroll
    for (int rr = 0; rr < 4; ++rr) acc[rr] = make_float4(0.f, 0.f, 0.f, 0.f);

    for (int d = 0; d < DIM; ++d) {
        const float4 w0 = *reinterpret_cast<const float4*>(W + 0 * DIM * DIM + d * DIM + cq * 4);
        const float4 w1 = *reinterpret_cast<const float4*>(W + 1 * DIM * DIM + d * DIM + cq * 4);
        const float4 w2 = *reinterpret_cast<const float4*>(W + 2 * DIM * DIM + d * DIM + cq * 4);
        const float4 w3 = *reinterpret_cast<const float4*>(W + 3 * DIM * DIM + d * DIM + cq * 4);
#pragma unroll
        for (int rr = 0; rr < 4; ++rr) {
            const int r = r0 + rr * 8;
            float t0 = sA[0][r][d], t1 = sA[1][r][d], t2 = sA[2][r][d], t3 = sA[3][r][d];
            acc[rr].x = fmaf(t0, w0.x, acc[rr].x); acc[rr].y = fmaf(t0, w0.y, acc[rr].y);
            acc[rr].z = fmaf(t0, w0.z, acc[rr].z); acc[rr].w = fmaf(t0, w0.w, acc[rr].w);
            acc[rr].x = fmaf(t1, w1.x, acc[rr].x); acc[rr].y = fmaf(t1, w1.y, acc[rr].y);
            acc[rr].z = fmaf(t1, w1.z, acc[rr].z); acc[rr].w = fmaf(t1, w1.w, acc[rr].w);
            acc[rr].x = fmaf(t2, w2.x, acc[rr].x); acc[rr].y = fmaf(t2, w2.y, acc[rr].y);
            acc[rr].z = fmaf(t2, w2.z, acc[rr].z); acc[rr].w = fmaf(t2, w2.w, acc[rr].w);
            acc[rr].x = fmaf(t3, w3.x, acc[rr].x); acc[rr].y = fmaf(t3, w3.y, acc[rr].y);
            acc[rr].z = fmaf(t3, w3.z, acc[rr].z); acc[rr].w = fmaf(t3, w3.w, acc[rr].w);
        }
    }

    const float4 b4 = *reinterpret_cast<const float4*>(bias + cq * 4);
#pragma unroll
    for (int rr = 0; rr < 4; ++rr) {
        const int g = row0 + r0 + rr * 8;
        if (g >= N) continue;
        float4 o = acc[rr];
        o.x += b4.x; o.y += b4.y; o.z += b4.z; o.w += b4.w;
        *reinterpret_cast<float4*>(out + (size_t)g * DIM + cq * 4) = o;
    }
}

// two-matrix fallback (ws too small for a third T buffer)
__global__ __launch_bounds__(192) void gemm2_kernel(
        const float* __restrict__ A, const float* __restrict__ B,
        const float* __restrict__ W0, const float* __restrict__ W1,
        const float* __restrict__ bias, float* __restrict__ out, int N, int accumulate) {
    __shared__ float sA[R_TILE][DIM + 1];
    __shared__ float sB[R_TILE][DIM + 1];
    const int tid = threadIdx.x;
    const int row0 = blockIdx.x * R_TILE;
    for (int l = tid; l < R_TILE * CHUNKS; l += 192) {
        int r = l / CHUNKS;
        int cq = l % CHUNKS;
        int g = row0 + r;
        float4 va = make_float4(0.f, 0.f, 0.f, 0.f);
        float4 vb = va;
        if (g < N) {
            va = *reinterpret_cast<const float4*>(A + (size_t)g * DIM + cq * 4);
            vb = *reinterpret_cast<const float4*>(B + (size_t)g * DIM + cq * 4);
        }
        sA[r][cq * 4 + 0] = va.x; sA[r][cq * 4 + 1] = va.y;
        sA[r][cq * 4 + 2] = va.z; sA[r][cq * 4 + 3] = va.w;
        sB[r][cq * 4 + 0] = vb.x; sB[r][cq * 4 + 1] = vb.y;
        sB[r][cq * 4 + 2] = vb.z; sB[r][cq * 4 + 3] = vb.w;
    }
    __syncthreads();
    const int cq = tid % CHUNKS;
    const int r0 = tid / CHUNKS;
    float4 acc[4];
#pragma unroll
    for (int rr = 0; rr < 4; ++rr) acc[rr] = make_float4(0.f, 0.f, 0.f, 0.f);
    for (int d = 0; d < DIM; ++d) {
        const float4 w0 = *reinterpret_cast<const float4*>(W0 + d * DIM + cq * 4);
        const float4 w1 = *reinterpret_cast<const float4*>(W1 + d * DIM + cq * 4);
#pragma unroll
        for (int rr = 0; rr < 4; ++rr) {
            const int r = r0 + rr * 8;
            float a = sA[r][d];
            float b = sB[r][d];
            acc[rr].x = fmaf(a, w0.x, acc[rr].x); acc[rr].y = fmaf(a, w0.y, acc[rr].y);
            acc[rr].z = fmaf(a, w0.z, acc[rr].z); acc[rr].w = fmaf(a, w0.w, acc[rr].w);
            acc[rr].x = fmaf(b, w1.x, acc[rr].x); acc[rr].y = fmaf(b, w1.y, acc[rr].y);
            acc[rr].z = fmaf(b, w1.z, acc[rr].z); acc[rr].w = fmaf(b, w1.w, acc[rr].w);
        }
    }
    const float4 b4 = *reinterpret_cast<const float4*>(bias + cq * 4);
#pragma unroll
    for (int rr = 0; rr < 4; ++rr) {
        const int g = row0 + r0 + rr * 8;
        if (g >= N) continue;
        float4 o = acc[rr];
        float* dst = out + (size_t)g * DIM + cq * 4;
        if (accumulate) {
            float4 p = *reinterpret_cast<const float4*>(dst);
            o.x += p.x; o.y += p.y; o.z += p.z; o.w += p.w;
        } else {
            o.x += b4.x; o.y += b4.y; o.z += b4.z; o.w += b4.w;
        }
        *reinterpret_cast<float4*>(dst) = o;
    }
}

extern "C" void kernel_launch(void* const* d_in, const int* in_sizes, int n_in,
                              void* d_out, int out_size, void* d_ws, size_t ws_size,
                              hipStream_t stream) {
    const float* x    = (const float*)d_in[0];
    const int*   ei   = (const int*)d_in[1];
    const float* w    = (const float*)d_in[2];
    const float* bias = (const float*)d_in[3];
    float* out = (float*)d_out;

    const int N = in_sizes[0] / DIM;   // 50000
    const int E = in_sizes[1] / 2;     // 800000
    const int* row = ei;
    const int* col = ei + E;

    // ---- workspace layout ----
    char* p = (char*)d_ws;
    auto alloc = [&](size_t bytes) { char* q = p; p += (bytes + 15) & ~(size_t)15; return q; };
    int*   degi      = (int*)  alloc((size_t)N * 4);   // degree (adjacent to fill: one memset)
    int*   fill      = (int*)  alloc((size_t)N * 4);   // CSR fill counters
    int*   offsets   = (int*)  alloc((size_t)(N + 1) * 4);
    float* dinv      = (float*)alloc((size_t)N * 4);
    int*   blocksums = (int*)  alloc(256 * 4);
    int*   colsorted = (int*)  alloc((size_t)E * 4);
    float* wsorted   = (float*)alloc((size_t)E * 4);
    float* T1        = (float*)alloc((size_t)N * DIM * 4);
    float* T2        = (float*)alloc((size_t)N * DIM * 4);
    char*  p_before_T3 = p;
    float* T3        = (float*)alloc((size_t)N * DIM * 4);
    const bool have_T3 = ((size_t)(p - (char*)d_ws) <= ws_size);
    if (!have_T3) p = p_before_T3;

    const int BLK = 256;
    const int grid_edges  = (E + BLK - 1) / BLK;
    const int grid_nodes  = (N + BLK - 1) / BLK;
    const int grid_gather = (N * CHUNKS + GBLK - 1) / GBLK;
    const int grid_gemm   = (N + R_TILE - 1) / R_TILE;
    const int nscan       = (N + SCAN_CHUNK - 1) / SCAN_CHUNK;

    // ---- build normalized CSR ----
    hipMemsetAsync(degi, 0, (size_t)2 * N * 4, stream);   // degi + fill in one shot
    deg_kernel<<<grid_edges, BLK, 0, stream>>>(row, E, degi);
    dinv_kernel<<<grid_nodes, BLK, 0, stream>>>(degi, dinv, N);
    scan_blocks_kernel<<<nscan, 256, 0, stream>>>(degi, offsets, blocksums, N);
    scan_sums_kernel<<<1, 256, 0, stream>>>(blocksums, nscan);
    scan_add_kernel<<<grid_nodes, 256, 0, stream>>>(offsets, blocksums, N, E);
    build_csr_kernel<<<grid_edges, BLK, 0, stream>>>(row, col, dinv, offsets, fill,
                                                     colsorted, wsorted, E);

    // ---- hops ----
    gather_kernel<<<grid_gather, GBLK, 0, stream>>>(offsets, colsorted, wsorted, dinv,
                                                    x, nullptr, T1, N, 1.0f);
    gather_kernel<<<grid_gather, GBLK, 0, stream>>>(offsets, colsorted, wsorted, dinv,
                                                    T1, x, T2, N, 2.0f);
    if (have_T3) {
        gather_kernel<<<grid_gather, GBLK, 0, stream>>>(offsets, colsorted, wsorted, dinv,
                                                        T2, T1, T3, N, 2.0f);
        gemm4_kernel<<<grid_gemm, 192, 0, stream>>>(x, T1, T2, T3, w, bias, out, N);
    } else {
        gemm2_kernel<<<grid_gemm, 192, 0, stream>>>(x, T1, w + 0 * DIM * DIM, w + 1 * DIM * DIM,
                                                    bias, out, N, 0);
        gather_kernel<<<grid_gather, GBLK, 0, stream>>>(offsets, colsorted, wsorted, dinv,
                                                        T2, T1, T1, N, 2.0f);
        gemm2_kernel<<<grid_gemm, 192, 0, stream>>>(T2, T1, w + 2 * DIM * DIM, w + 3 * DIM * DIM,
                                                    bias, out, N, 1);
    }
}

// Round 6
// 362.823 us; speedup vs baseline: 1.0515x; 1.0515x over previous
//
#include <hip/hip_runtime.h>

#define DIM 96
#define CHUNKS 24   // DIM / 4 float4 chunks per node row
#define GBLK 192    // 8 nodes per block in gather
#define R4 16       // rows per block in fused 4-matrix GEMM
#define R_TILE 32   // rows per block in fallback GEMM
#define SCAN_CHUNK 1024

// ---------------------------------------------------------------------------
__global__ void deg_kernel(const int* __restrict__ row, int E, int* __restrict__ degi) {
    int e = blockIdx.x * blockDim.x + threadIdx.x;
    if (e < E) atomicAdd(&degi[row[e]], 1);
}

__global__ void dinv_kernel(const int* __restrict__ degi, float* __restrict__ dinv, int N) {
    int i = blockIdx.x * blockDim.x + threadIdx.x;
    if (i < N) {
        int d = degi[i];
        dinv[i] = (d > 0) ? rsqrtf((float)d) : 0.0f;
    }
}

// ---- multi-block exclusive scan of degi -> offsets ----
__global__ __launch_bounds__(256) void scan_blocks_kernel(
        const int* __restrict__ degi, int* __restrict__ offsets,
        int* __restrict__ blocksums, int N) {
    __shared__ int s[256];
    const int t = threadIdx.x;
    const int base = blockIdx.x * SCAN_CHUNK + t * 4;
    int v0 = 0, v1 = 0, v2 = 0, v3 = 0;
    if (base + 3 < N) {
        const int4 q = *reinterpret_cast<const int4*>(degi + base);
        v0 = q.x; v1 = q.y; v2 = q.z; v3 = q.w;
    } else {
        if (base + 0 < N) v0 = degi[base + 0];
        if (base + 1 < N) v1 = degi[base + 1];
        if (base + 2 < N) v2 = degi[base + 2];
        if (base + 3 < N) v3 = degi[base + 3];
    }
    const int mysum = v0 + v1 + v2 + v3;
    s[t] = mysum;
    __syncthreads();
    for (int off = 1; off < 256; off <<= 1) {
        int x = (t >= off) ? s[t - off] : 0;
        __syncthreads();
        s[t] += x;
        __syncthreads();
    }
    int run = s[t] - mysum;
    if (t == 255) blocksums[blockIdx.x] = s[255];
    if (base + 0 < N) offsets[base + 0] = run;  run += v0;
    if (base + 1 < N) offsets[base + 1] = run;  run += v1;
    if (base + 2 < N) offsets[base + 2] = run;  run += v2;
    if (base + 3 < N) offsets[base + 3] = run;
}

__global__ __launch_bounds__(256) void scan_sums_kernel(int* __restrict__ blocksums, int nb) {
    __shared__ int s[256];
    const int t = threadIdx.x;
    const int v = (t < nb) ? blocksums[t] : 0;
    s[t] = v;
    __syncthreads();
    for (int off = 1; off < 256; off <<= 1) {
        int x = (t >= off) ? s[t - off] : 0;
        __syncthreads();
        s[t] += x;
        __syncthreads();
    }
    if (t < nb) blocksums[t] = s[t] - v;
}

__global__ __launch_bounds__(256) void scan_add_kernel(
        int* __restrict__ offsets, const int* __restrict__ blocksums, int N, int E) {
    const int i = blockIdx.x * blockDim.x + threadIdx.x;
    if (i < N) offsets[i] += blocksums[i >> 10];  // SCAN_CHUNK == 1024
    if (i == 0) offsets[N] = E;
}

// place each edge into its row segment; pack {col, dinv[col]} in one int2
__global__ void build_csr_kernel(const int* __restrict__ row, const int* __restrict__ col,
                                 const float* __restrict__ dinv, const int* __restrict__ offsets,
                                 int* __restrict__ fill, int2* __restrict__ cw, int E) {
    int e = blockIdx.x * blockDim.x + threadIdx.x;
    if (e >= E) return;
    int r = row[e];
    int p = offsets[r] + atomicAdd(&fill[r], 1);
    int c = col[e];
    cw[p] = make_int2(c, __float_as_int(dinv[c]));
}

// dst[i][:] = -scale*dinv[i]*sum_e w[e]*h[col[e]][:] (- prev[i][:])
// 4x unrolled: 4 independent row-gathers in flight per thread.
__global__ __launch_bounds__(GBLK) void gather_kernel(
        const int* __restrict__ offsets, const int2* __restrict__ cw,
        const float* __restrict__ dinv,
        const float* __restrict__ h, const float* __restrict__ prev,
        float* __restrict__ dst, int N, float scale) {
    int tid = blockIdx.x * blockDim.x + threadIdx.x;
    int node = tid / CHUNKS;
    int c = tid % CHUNKS;
    if (node >= N) return;
    int s = offsets[node];
    int e = offsets[node + 1];
    const float* hc = h + c * 4;

    float4 a0 = make_float4(0.f, 0.f, 0.f, 0.f);
    float4 a1 = a0, a2 = a0, a3 = a0;
    int k = s;
    for (; k + 3 < e; k += 4) {
        int2 c0 = cw[k + 0], c1 = cw[k + 1], c2 = cw[k + 2], c3 = cw[k + 3];
        const float4 v0 = *reinterpret_cast<const float4*>(hc + (size_t)c0.x * DIM);
        const float4 v1 = *reinterpret_cast<const float4*>(hc + (size_t)c1.x * DIM);
        const float4 v2 = *reinterpret_cast<const float4*>(hc + (size_t)c2.x * DIM);
        const float4 v3 = *reinterpret_cast<const float4*>(hc + (size_t)c3.x * DIM);
        float w0 = __int_as_float(c0.y), w1 = __int_as_float(c1.y);
        float w2 = __int_as_float(c2.y), w3 = __int_as_float(c3.y);
        a0.x = fmaf(w0, v0.x, a0.x); a0.y = fmaf(w0, v0.y, a0.y);
        a0.z = fmaf(w0, v0.z, a0.z); a0.w = fmaf(w0, v0.w, a0.w);
        a1.x = fmaf(w1, v1.x, a1.x); a1.y = fmaf(w1, v1.y, a1.y);
        a1.z = fmaf(w1, v1.z, a1.z); a1.w = fmaf(w1, v1.w, a1.w);
        a2.x = fmaf(w2, v2.x, a2.x); a2.y = fmaf(w2, v2.y, a2.y);
        a2.z = fmaf(w2, v2.z, a2.z); a2.w = fmaf(w2, v2.w, a2.w);
        a3.x = fmaf(w3, v3.x, a3.x); a3.y = fmaf(w3, v3.y, a3.y);
        a3.z = fmaf(w3, v3.z, a3.z); a3.w = fmaf(w3, v3.w, a3.w);
    }
    for (; k < e; ++k) {
        int2 c0 = cw[k];
        float w0 = __int_as_float(c0.y);
        const float4 v0 = *reinterpret_cast<const float4*>(hc + (size_t)c0.x * DIM);
        a0.x = fmaf(w0, v0.x, a0.x); a0.y = fmaf(w0, v0.y, a0.y);
        a0.z = fmaf(w0, v0.z, a0.z); a0.w = fmaf(w0, v0.w, a0.w);
    }
    float ax = (a0.x + a1.x) + (a2.x + a3.x);
    float ay = (a0.y + a1.y) + (a2.y + a3.y);
    float az = (a0.z + a1.z) + (a2.z + a3.z);
    float aw = (a0.w + a1.w) + (a2.w + a3.w);

    float m = -scale * dinv[node];
    float4 o = make_float4(m * ax, m * ay, m * az, m * aw);
    if (prev) {
        const float4 p = *reinterpret_cast<const float4*>(prev + (size_t)node * DIM + c * 4);
        o.x -= p.x; o.y -= p.y; o.z -= p.z; o.w -= p.w;
    }
    *reinterpret_cast<float4*>(dst + (size_t)node * DIM + c * 4) = o;
}

// Fused four-matrix GEMM: out = bias + A0@W0 + A1@W1 + A2@W2 + A3@W3
// R4=16 rows/block -> 26.6 KB LDS -> 6 blocks/CU. Thread: 2 rows x 4 cols.
__global__ __launch_bounds__(192) void gemm4_kernel(
        const float* __restrict__ A0, const float* __restrict__ A1,
        const float* __restrict__ A2, const float* __restrict__ A3,
        const float* __restrict__ W,   // [4][DIM][DIM]
        const float* __restrict__ bias, float* __restrict__ out, int N) {
    __shared__ __align__(16) float sA[4][R4][DIM + 8];  // +8: 16B-aligned rows, bank-offset 8
    const int tid = threadIdx.x;
    const int row0 = blockIdx.x * R4;
    const float* As[4] = {A0, A1, A2, A3};

    for (int l = tid; l < 4 * R4 * CHUNKS; l += 192) {
        int m = l / (R4 * CHUNKS);
        int rem = l % (R4 * CHUNKS);
        int r = rem / CHUNKS;
        int cq = rem % CHUNKS;
        int g = row0 + r;
        float4 v = make_float4(0.f, 0.f, 0.f, 0.f);
        if (g < N) v = *reinterpret_cast<const float4*>(As[m] + (size_t)g * DIM + cq * 4);
        *reinterpret_cast<float4*>(&sA[m][r][cq * 4]) = v;
    }
    __syncthreads();

    const int cq = tid % CHUNKS;       // col chunk 0..23
    const int r0 = tid / CHUNKS;       // row slot 0..7; rows r0 and r0+8
    float4 acc0 = make_float4(0.f, 0.f, 0.f, 0.f);
    float4 acc1 = acc0;

    for (int d = 0; d < DIM; d += 4) {
#pragma unroll
        for (int m = 0; m < 4; ++m) {
            const float4 t0 = *reinterpret_cast<const float4*>(&sA[m][r0][d]);
            const float4 t1 = *reinterpret_cast<const float4*>(&sA[m][r0 + 8][d]);
            const float* wb = W + m * DIM * DIM + d * DIM + cq * 4;
            const float4 w0 = *reinterpret_cast<const float4*>(wb + 0 * DIM);
            const float4 w1 = *reinterpret_cast<const float4*>(wb + 1 * DIM);
            const float4 w2 = *reinterpret_cast<const float4*>(wb + 2 * DIM);
            const float4 w3 = *reinterpret_cast<const float4*>(wb + 3 * DIM);
            acc0.x = fmaf(t0.x, w0.x, acc0.x); acc0.y = fmaf(t0.x, w0.y, acc0.y);
            acc0.z = fmaf(t0.x, w0.z, acc0.z); acc0.w = fmaf(t0.x, w0.w, acc0.w);
            acc1.x = fmaf(t1.x, w0.x, acc1.x); acc1.y = fmaf(t1.x, w0.y, acc1.y);
            acc1.z = fmaf(t1.x, w0.z, acc1.z); acc1.w = fmaf(t1.x, w0.w, acc1.w);
            acc0.x = fmaf(t0.y, w1.x, acc0.x); acc0.y = fmaf(t0.y, w1.y, acc0.y);
            acc0.z = fmaf(t0.y, w1.z, acc0.z); acc0.w = fmaf(t0.y, w1.w, acc0.w);
            acc1.x = fmaf(t1.y, w1.x, acc1.x); acc1.y = fmaf(t1.y, w1.y, acc1.y);
            acc1.z = fmaf(t1.y, w1.z, acc1.z); acc1.w = fmaf(t1.y, w1.w, acc1.w);
            acc0.x = fmaf(t0.z, w2.x, acc0.x); acc0.y = fmaf(t0.z, w2.y, acc0.y);
            acc0.z = fmaf(t0.z, w2.z, acc0.z); acc0.w = fmaf(t0.z, w2.w, acc0.w);
            acc1.x = fmaf(t1.z, w2.x, acc1.x); acc1.y = fmaf(t1.z, w2.y, acc1.y);
            acc1.z = fmaf(t1.z, w2.z, acc1.z); acc1.w = fmaf(t1.z, w2.w, acc1.w);
            acc0.x = fmaf(t0.w, w3.x, acc0.x); acc0.y = fmaf(t0.w, w3.y, acc0.y);
            acc0.z = fmaf(t0.w, w3.z, acc0.z); acc0.w = fmaf(t0.w, w3.w, acc0.w);
            acc1.x = fmaf(t1.w, w3.x, acc1.x); acc1.y = fmaf(t1.w, w3.y, acc1.y);
            acc1.z = fmaf(t1.w, w3.z, acc1.z); acc1.w = fmaf(t1.w, w3.w, acc1.w);
        }
    }

    const float4 b4 = *reinterpret_cast<const float4*>(bias + cq * 4);
    {
        const int g = row0 + r0;
        if (g < N) {
            float4 o = acc0;
            o.x += b4.x; o.y += b4.y; o.z += b4.z; o.w += b4.w;
            *reinterpret_cast<float4*>(out + (size_t)g * DIM + cq * 4) = o;
        }
    }
    {
        const int g = row0 + r0 + 8;
        if (g < N) {
            float4 o = acc1;
            o.x += b4.x; o.y += b4.y; o.z += b4.z; o.w += b4.w;
            *reinterpret_cast<float4*>(out + (size_t)g * DIM + cq * 4) = o;
        }
    }
}

// two-matrix fallback (ws too small for a third T buffer)
__global__ __launch_bounds__(192) void gemm2_kernel(
        const float* __restrict__ A, const float* __restrict__ B,
        const float* __restrict__ W0, const float* __restrict__ W1,
        const float* __restrict__ bias, float* __restrict__ out, int N, int accumulate) {
    __shared__ float sA[R_TILE][DIM + 1];
    __shared__ float sB[R_TILE][DIM + 1];
    const int tid = threadIdx.x;
    const int row0 = blockIdx.x * R_TILE;
    for (int l = tid; l < R_TILE * CHUNKS; l += 192) {
        int r = l / CHUNKS;
        int cq = l % CHUNKS;
        int g = row0 + r;
        float4 va = make_float4(0.f, 0.f, 0.f, 0.f);
        float4 vb = va;
        if (g < N) {
            va = *reinterpret_cast<const float4*>(A + (size_t)g * DIM + cq * 4);
            vb = *reinterpret_cast<const float4*>(B + (size_t)g * DIM + cq * 4);
        }
        sA[r][cq * 4 + 0] = va.x; sA[r][cq * 4 + 1] = va.y;
        sA[r][cq * 4 + 2] = va.z; sA[r][cq * 4 + 3] = va.w;
        sB[r][cq * 4 + 0] = vb.x; sB[r][cq * 4 + 1] = vb.y;
        sB[r][cq * 4 + 2] = vb.z; sB[r][cq * 4 + 3] = vb.w;
    }
    __syncthreads();
    const int cq = tid % CHUNKS;
    const int r0 = tid / CHUNKS;
    float4 acc[4];
#pragma unroll
    for (int rr = 0; rr < 4; ++rr) acc[rr] = make_float4(0.f, 0.f, 0.f, 0.f);
    for (int d = 0; d < DIM; ++d) {
        const float4 w0 = *reinterpret_cast<const float4*>(W0 + d * DIM + cq * 4);
        const float4 w1 = *reinterpret_cast<const float4*>(W1 + d * DIM + cq * 4);
#pragma unroll
        for (int rr = 0; rr < 4; ++rr) {
            const int r = r0 + rr * 8;
            float a = sA[r][d];
            float b = sB[r][d];
            acc[rr].x = fmaf(a, w0.x, acc[rr].x); acc[rr].y = fmaf(a, w0.y, acc[rr].y);
            acc[rr].z = fmaf(a, w0.z, acc[rr].z); acc[rr].w = fmaf(a, w0.w, acc[rr].w);
            acc[rr].x = fmaf(b, w1.x, acc[rr].x); acc[rr].y = fmaf(b, w1.y, acc[rr].y);
            acc[rr].z = fmaf(b, w1.z, acc[rr].z); acc[rr].w = fmaf(b, w1.w, acc[rr].w);
        }
    }
    const float4 b4 = *reinterpret_cast<const float4*>(bias + cq * 4);
#pragma unroll
    for (int rr = 0; rr < 4; ++rr) {
        const int g = row0 + r0 + rr * 8;
        if (g >= N) continue;
        float4 o = acc[rr];
        float* dst = out + (size_t)g * DIM + cq * 4;
        if (accumulate) {
            float4 p = *reinterpret_cast<const float4*>(dst);
            o.x += p.x; o.y += p.y; o.z += p.z; o.w += p.w;
        } else {
            o.x += b4.x; o.y += b4.y; o.z += b4.z; o.w += b4.w;
        }
        *reinterpret_cast<float4*>(dst) = o;
    }
}

extern "C" void kernel_launch(void* const* d_in, const int* in_sizes, int n_in,
                              void* d_out, int out_size, void* d_ws, size_t ws_size,
                              hipStream_t stream) {
    const float* x    = (const float*)d_in[0];
    const int*   ei   = (const int*)d_in[1];
    const float* w    = (const float*)d_in[2];
    const float* bias = (const float*)d_in[3];
    float* out = (float*)d_out;

    const int N = in_sizes[0] / DIM;   // 50000
    const int E = in_sizes[1] / 2;     // 800000
    const int* row = ei;
    const int* col = ei + E;

    // ---- workspace layout ----
    char* p = (char*)d_ws;
    auto alloc = [&](size_t bytes) { char* q = p; p += (bytes + 15) & ~(size_t)15; return q; };
    int*   degi      = (int*)  alloc((size_t)N * 4);   // degree (adjacent to fill: one memset)
    int*   fill      = (int*)  alloc((size_t)N * 4);   // CSR fill counters
    int*   offsets   = (int*)  alloc((size_t)(N + 1) * 4);
    float* dinv      = (float*)alloc((size_t)N * 4);
    int*   blocksums = (int*)  alloc(256 * 4);
    int2*  cw        = (int2*) alloc((size_t)E * 8);   // packed {col, dinv[col]}
    float* T1        = (float*)alloc((size_t)N * DIM * 4);
    float* T2        = (float*)alloc((size_t)N * DIM * 4);
    char*  p_before_T3 = p;
    float* T3        = (float*)alloc((size_t)N * DIM * 4);
    const bool have_T3 = ((size_t)(p - (char*)d_ws) <= ws_size);
    if (!have_T3) p = p_before_T3;

    const int BLK = 256;
    const int grid_edges  = (E + BLK - 1) / BLK;
    const int grid_nodes  = (N + BLK - 1) / BLK;
    const int grid_gather = (N * CHUNKS + GBLK - 1) / GBLK;
    const int grid_gemm4  = (N + R4 - 1) / R4;
    const int grid_gemm2  = (N + R_TILE - 1) / R_TILE;
    const int nscan       = (N + SCAN_CHUNK - 1) / SCAN_CHUNK;

    // ---- build normalized CSR ----
    hipMemsetAsync(degi, 0, (size_t)2 * N * 4, stream);   // degi + fill in one shot
    deg_kernel<<<grid_edges, BLK, 0, stream>>>(row, E, degi);
    dinv_kernel<<<grid_nodes, BLK, 0, stream>>>(degi, dinv, N);
    scan_blocks_kernel<<<nscan, 256, 0, stream>>>(degi, offsets, blocksums, N);
    scan_sums_kernel<<<1, 256, 0, stream>>>(blocksums, nscan);
    scan_add_kernel<<<grid_nodes, 256, 0, stream>>>(offsets, blocksums, N, E);
    build_csr_kernel<<<grid_edges, BLK, 0, stream>>>(row, col, dinv, offsets, fill, cw, E);

    // ---- hops ----
    gather_kernel<<<grid_gather, GBLK, 0, stream>>>(offsets, cw, dinv, x, nullptr, T1, N, 1.0f);
    gather_kernel<<<grid_gather, GBLK, 0, stream>>>(offsets, cw, dinv, T1, x, T2, N, 2.0f);
    if (have_T3) {
        gather_kernel<<<grid_gather, GBLK, 0, stream>>>(offsets, cw, dinv, T2, T1, T3, N, 2.0f);
        gemm4_kernel<<<grid_gemm4, 192, 0, stream>>>(x, T1, T2, T3, w, bias, out, N);
    } else {
        gemm2_kernel<<<grid_gemm2, 192, 0, stream>>>(x, T1, w + 0 * DIM * DIM, w + 1 * DIM * DIM,
                                                     bias, out, N, 0);
        gather_kernel<<<grid_gather, GBLK, 0, stream>>>(offsets, cw, dinv, T2, T1, T1, N, 2.0f);
        gemm2_kernel<<<grid_gemm2, 192, 0, stream>>>(T2, T1, w + 2 * DIM * DIM, w + 3 * DIM * DIM,
                                                     bias, out, N, 1);
    }
}

// Round 7
// 228.194 us; speedup vs baseline: 1.6719x; 1.5900x over previous
//
#include <hip/hip_runtime.h>

#define DIM 96
#define BCH 12          // bf16 chunks of 8 elems per node row
#define GBLK 192        // 16 nodes per block in gather
#define SCAN_CHUNK 1024

typedef __attribute__((ext_vector_type(8))) short bf16x8;
typedef __attribute__((ext_vector_type(4))) float f32x4;

__device__ __forceinline__ float bflo(unsigned u) { return __uint_as_float(u << 16); }
__device__ __forceinline__ float bfhi(unsigned u) { return __uint_as_float(u & 0xffff0000u); }
__device__ __forceinline__ unsigned f2bf(float f) {            // RNE f32 -> bf16 bits
    unsigned u = __float_as_uint(f);
    return (u + 0x7fffu + ((u >> 16) & 1u)) >> 16;
}
__device__ __forceinline__ unsigned packbf(float lo, float hi) {
    return (f2bf(lo) & 0xffffu) | (f2bf(hi) << 16);
}

// ---------------------------------------------------------------------------
__global__ void deg_kernel(const int* __restrict__ row, int E, int* __restrict__ degi) {
    int e = blockIdx.x * blockDim.x + threadIdx.x;
    if (e < E) atomicAdd(&degi[row[e]], 1);
}

__global__ void dinv_kernel(const int* __restrict__ degi, float* __restrict__ dinv, int N) {
    int i = blockIdx.x * blockDim.x + threadIdx.x;
    if (i < N) {
        int d = degi[i];
        dinv[i] = (d > 0) ? rsqrtf((float)d) : 0.0f;
    }
}

// ---- multi-block exclusive scan of degi -> offsets ----
__global__ __launch_bounds__(256) void scan_blocks_kernel(
        const int* __restrict__ degi, int* __restrict__ offsets,
        int* __restrict__ blocksums, int N) {
    __shared__ int s[256];
    const int t = threadIdx.x;
    const int base = blockIdx.x * SCAN_CHUNK + t * 4;
    int v0 = 0, v1 = 0, v2 = 0, v3 = 0;
    if (base + 3 < N) {
        const int4 q = *reinterpret_cast<const int4*>(degi + base);
        v0 = q.x; v1 = q.y; v2 = q.z; v3 = q.w;
    } else {
        if (base + 0 < N) v0 = degi[base + 0];
        if (base + 1 < N) v1 = degi[base + 1];
        if (base + 2 < N) v2 = degi[base + 2];
        if (base + 3 < N) v3 = degi[base + 3];
    }
    const int mysum = v0 + v1 + v2 + v3;
    s[t] = mysum;
    __syncthreads();
    for (int off = 1; off < 256; off <<= 1) {
        int x = (t >= off) ? s[t - off] : 0;
        __syncthreads();
        s[t] += x;
        __syncthreads();
    }
    int run = s[t] - mysum;
    if (t == 255) blocksums[blockIdx.x] = s[255];
    if (base + 0 < N) offsets[base + 0] = run;  run += v0;
    if (base + 1 < N) offsets[base + 1] = run;  run += v1;
    if (base + 2 < N) offsets[base + 2] = run;  run += v2;
    if (base + 3 < N) offsets[base + 3] = run;
}

__global__ __launch_bounds__(256) void scan_sums_kernel(int* __restrict__ blocksums, int nb) {
    __shared__ int s[256];
    const int t = threadIdx.x;
    const int v = (t < nb) ? blocksums[t] : 0;
    s[t] = v;
    __syncthreads();
    for (int off = 1; off < 256; off <<= 1) {
        int x = (t >= off) ? s[t - off] : 0;
        __syncthreads();
        s[t] += x;
        __syncthreads();
    }
    if (t < nb) blocksums[t] = s[t] - v;
}

__global__ __launch_bounds__(256) void scan_add_kernel(
        int* __restrict__ offsets, const int* __restrict__ blocksums, int N, int E) {
    const int i = blockIdx.x * blockDim.x + threadIdx.x;
    if (i < N) offsets[i] += blocksums[i >> 10];  // SCAN_CHUNK == 1024
    if (i == 0) offsets[N] = E;
}

// place each edge into its row segment; pack {col, dinv[col]} in one int2
__global__ void build_csr_kernel(const int* __restrict__ row, const int* __restrict__ col,
                                 const float* __restrict__ dinv, const int* __restrict__ offsets,
                                 int* __restrict__ fill, int2* __restrict__ cw, int E) {
    int e = blockIdx.x * blockDim.x + threadIdx.x;
    if (e >= E) return;
    int r = row[e];
    int p = offsets[r] + atomicAdd(&fill[r], 1);
    int c = col[e];
    cw[p] = make_int2(c, __float_as_int(dinv[c]));
}

// x (fp32, N rows) -> xb (bf16, NPAD rows, zero-padded)
__global__ __launch_bounds__(256) void cvt_x_kernel(const float* __restrict__ x,
        ushort* __restrict__ xb, int N, int NPAD) {
    int i = blockIdx.x * blockDim.x + threadIdx.x;
    if (i >= NPAD * BCH) return;
    int g = i / BCH, c = i % BCH;
    uint4 o;
    if (g < N) {
        const float4 f0 = *reinterpret_cast<const float4*>(x + (size_t)g * DIM + c * 8);
        const float4 f1 = *reinterpret_cast<const float4*>(x + (size_t)g * DIM + c * 8 + 4);
        o.x = packbf(f0.x, f0.y); o.y = packbf(f0.z, f0.w);
        o.z = packbf(f1.x, f1.y); o.w = packbf(f1.z, f1.w);
    } else {
        o = make_uint4(0u, 0u, 0u, 0u);
    }
    *reinterpret_cast<uint4*>(xb + (size_t)g * DIM + c * 8) = o;
}

// W [4][k][n] fp32 -> Wt [4][n][k] bf16 (k contiguous for MFMA B-fragments)
__global__ __launch_bounds__(256) void cvt_w_kernel(const float* __restrict__ w,
        ushort* __restrict__ wt) {
    int i = blockIdx.x * blockDim.x + threadIdx.x;
    if (i >= 4 * DIM * DIM) return;
    int m = i / (DIM * DIM), rem = i % (DIM * DIM);
    int n = rem / DIM, k = rem % DIM;
    wt[i] = (ushort)f2bf(w[m * DIM * DIM + k * DIM + n]);
}

// dst[i][:] = bf16( -scale*dinv[i]*sum_e w[e]*h[col[e]][:] (- prev[i][:]) )
// bf16 rows, BCH=12 chunks of 8; 4x unrolled independent gathers.
__global__ __launch_bounds__(GBLK) void gather_bf_kernel(
        const int* __restrict__ offsets, const int2* __restrict__ cw,
        const float* __restrict__ dinv,
        const ushort* __restrict__ h, const ushort* __restrict__ prev,
        ushort* __restrict__ dst, int N, float scale) {
    int tid = blockIdx.x * blockDim.x + threadIdx.x;
    int node = tid / BCH;
    int c = tid % BCH;
    if (node >= N) return;
    int s = offsets[node];
    int e = offsets[node + 1];
    const ushort* hc = h + c * 8;

    float a[4][8];
#pragma unroll
    for (int u = 0; u < 4; ++u)
#pragma unroll
        for (int j = 0; j < 8; ++j) a[u][j] = 0.f;

    int k = s;
    for (; k + 3 < e; k += 4) {
        int2 cc[4];
        uint4 v[4];
#pragma unroll
        for (int u = 0; u < 4; ++u) cc[u] = cw[k + u];
#pragma unroll
        for (int u = 0; u < 4; ++u)
            v[u] = *reinterpret_cast<const uint4*>(hc + (size_t)cc[u].x * DIM);
#pragma unroll
        for (int u = 0; u < 4; ++u) {
            float wgt = __int_as_float(cc[u].y);
            a[u][0] = fmaf(wgt, bflo(v[u].x), a[u][0]);
            a[u][1] = fmaf(wgt, bfhi(v[u].x), a[u][1]);
            a[u][2] = fmaf(wgt, bflo(v[u].y), a[u][2]);
            a[u][3] = fmaf(wgt, bfhi(v[u].y), a[u][3]);
            a[u][4] = fmaf(wgt, bflo(v[u].z), a[u][4]);
            a[u][5] = fmaf(wgt, bfhi(v[u].z), a[u][5]);
            a[u][6] = fmaf(wgt, bflo(v[u].w), a[u][6]);
            a[u][7] = fmaf(wgt, bfhi(v[u].w), a[u][7]);
        }
    }
    for (; k < e; ++k) {
        int2 c0 = cw[k];
        uint4 v0 = *reinterpret_cast<const uint4*>(hc + (size_t)c0.x * DIM);
        float wgt = __int_as_float(c0.y);
        a[0][0] = fmaf(wgt, bflo(v0.x), a[0][0]);
        a[0][1] = fmaf(wgt, bfhi(v0.x), a[0][1]);
        a[0][2] = fmaf(wgt, bflo(v0.y), a[0][2]);
        a[0][3] = fmaf(wgt, bfhi(v0.y), a[0][3]);
        a[0][4] = fmaf(wgt, bflo(v0.z), a[0][4]);
        a[0][5] = fmaf(wgt, bfhi(v0.z), a[0][5]);
        a[0][6] = fmaf(wgt, bflo(v0.w), a[0][6]);
        a[0][7] = fmaf(wgt, bfhi(v0.w), a[0][7]);
    }

    float m = -scale * dinv[node];
    float o[8];
#pragma unroll
    for (int j = 0; j < 8; ++j)
        o[j] = m * ((a[0][j] + a[1][j]) + (a[2][j] + a[3][j]));
    if (prev) {
        uint4 pv = *reinterpret_cast<const uint4*>(prev + (size_t)node * DIM + c * 8);
        o[0] -= bflo(pv.x); o[1] -= bfhi(pv.x);
        o[2] -= bflo(pv.y); o[3] -= bfhi(pv.y);
        o[4] -= bflo(pv.z); o[5] -= bfhi(pv.z);
        o[6] -= bflo(pv.w); o[7] -= bfhi(pv.w);
    }
    uint4 ov;
    ov.x = packbf(o[0], o[1]); ov.y = packbf(o[2], o[3]);
    ov.z = packbf(o[4], o[5]); ov.w = packbf(o[6], o[7]);
    *reinterpret_cast<uint4*>(dst + (size_t)node * DIM + c * 8) = ov;
}

// out[M=N][96] = bias + sum_m A_m @ W_m  via mfma_f32_16x16x32_bf16.
// 4 waves/block, 16 rows/wave, 6 col-tiles of 16; K=96 per matrix (3 steps of 32).
__global__ __launch_bounds__(256) void mfma_gemm_kernel(
        const ushort* __restrict__ A0, const ushort* __restrict__ A1,
        const ushort* __restrict__ A2, const ushort* __restrict__ A3,
        const ushort* __restrict__ Wt, const float* __restrict__ bias,
        float* __restrict__ out, int N) {
    const int wave = threadIdx.x >> 6;
    const int lane = threadIdx.x & 63;
    const int r  = lane & 15;    // A-row / B-col within tile
    const int kg = lane >> 4;    // k-group (8 elems each)
    const int row0 = blockIdx.x * 64 + wave * 16;
    const ushort* As[4] = {A0, A1, A2, A3};

    f32x4 acc[6];
#pragma unroll
    for (int n = 0; n < 6; ++n) acc[n] = (f32x4){0.f, 0.f, 0.f, 0.f};

#pragma unroll
    for (int m = 0; m < 4; ++m) {
        const ushort* Ap = As[m] + (size_t)(row0 + r) * DIM + kg * 8;
        const ushort* Wp = Wt + m * DIM * DIM + r * DIM + kg * 8;
#pragma unroll
        for (int ks = 0; ks < 3; ++ks) {
            bf16x8 af = *reinterpret_cast<const bf16x8*>(Ap + ks * 32);
#pragma unroll
            for (int n = 0; n < 6; ++n) {
                bf16x8 bfr = *reinterpret_cast<const bf16x8*>(Wp + n * 16 * DIM + ks * 32);
                acc[n] = __builtin_amdgcn_mfma_f32_16x16x32_bf16(af, bfr, acc[n], 0, 0, 0);
            }
        }
    }

    // C/D layout: col = lane&15, row = (lane>>4)*4 + reg
#pragma unroll
    for (int n = 0; n < 6; ++n) {
        const float bz = bias[n * 16 + r];
#pragma unroll
        for (int j = 0; j < 4; ++j) {
            int gr = row0 + kg * 4 + j;
            if (gr < N) out[(size_t)gr * DIM + n * 16 + r] = acc[n][j] + bz;
        }
    }
}

extern "C" void kernel_launch(void* const* d_in, const int* in_sizes, int n_in,
                              void* d_out, int out_size, void* d_ws, size_t ws_size,
                              hipStream_t stream) {
    const float* x    = (const float*)d_in[0];
    const int*   ei   = (const int*)d_in[1];
    const float* w    = (const float*)d_in[2];
    const float* bias = (const float*)d_in[3];
    float* out = (float*)d_out;

    const int N = in_sizes[0] / DIM;   // 50000
    const int E = in_sizes[1] / 2;     // 800000
    const int NPAD = (N + 63) & ~63;   // pad rows for 64-row MFMA blocks
    const int* row = ei;
    const int* col = ei + E;

    // ---- workspace layout ----
    char* p = (char*)d_ws;
    auto alloc = [&](size_t bytes) { char* q = p; p += (bytes + 15) & ~(size_t)15; return q; };
    int*    degi      = (int*)   alloc((size_t)N * 4);   // degree (adjacent to fill)
    int*    fill      = (int*)   alloc((size_t)N * 4);   // CSR fill counters
    int*    offsets   = (int*)   alloc((size_t)(N + 1) * 4);
    float*  dinv      = (float*) alloc((size_t)N * 4);
    int*    blocksums = (int*)   alloc(256 * 4);
    int2*   cw        = (int2*)  alloc((size_t)E * 8);
    ushort* xb        = (ushort*)alloc((size_t)NPAD * DIM * 2);
    ushort* T1        = (ushort*)alloc((size_t)NPAD * DIM * 2);
    ushort* T2        = (ushort*)alloc((size_t)NPAD * DIM * 2);
    ushort* T3        = (ushort*)alloc((size_t)NPAD * DIM * 2);
    ushort* Wt        = (ushort*)alloc((size_t)4 * DIM * DIM * 2);

    const int BLK = 256;
    const int grid_edges  = (E + BLK - 1) / BLK;
    const int grid_nodes  = (N + BLK - 1) / BLK;
    const int grid_gather = (N * BCH + GBLK - 1) / GBLK;
    const int grid_cvtx   = (NPAD * BCH + BLK - 1) / BLK;
    const int grid_cvtw   = (4 * DIM * DIM + BLK - 1) / BLK;
    const int grid_mfma   = NPAD / 64;
    const int nscan       = (N + SCAN_CHUNK - 1) / SCAN_CHUNK;

    // ---- build normalized CSR ----
    hipMemsetAsync(degi, 0, (size_t)2 * N * 4, stream);   // degi + fill in one shot
    deg_kernel<<<grid_edges, BLK, 0, stream>>>(row, E, degi);
    dinv_kernel<<<grid_nodes, BLK, 0, stream>>>(degi, dinv, N);
    scan_blocks_kernel<<<nscan, 256, 0, stream>>>(degi, offsets, blocksums, N);
    scan_sums_kernel<<<1, 256, 0, stream>>>(blocksums, nscan);
    scan_add_kernel<<<grid_nodes, 256, 0, stream>>>(offsets, blocksums, N, E);
    build_csr_kernel<<<grid_edges, BLK, 0, stream>>>(row, col, dinv, offsets, fill, cw, E);

    // ---- bf16 conversions ----
    cvt_x_kernel<<<grid_cvtx, BLK, 0, stream>>>(x, xb, N, NPAD);
    cvt_w_kernel<<<grid_cvtw, BLK, 0, stream>>>(w, Wt);

    // ---- hops (bf16 in/out, fp32 accum) ----
    gather_bf_kernel<<<grid_gather, GBLK, 0, stream>>>(offsets, cw, dinv, xb, nullptr, T1, N, 1.0f);
    gather_bf_kernel<<<grid_gather, GBLK, 0, stream>>>(offsets, cw, dinv, T1, xb, T2, N, 2.0f);
    gather_bf_kernel<<<grid_gather, GBLK, 0, stream>>>(offsets, cw, dinv, T2, T1, T3, N, 2.0f);

    // ---- fused MFMA GEMM: out = bias + xb@W0 + T1@W1 + T2@W2 + T3@W3 ----
    mfma_gemm_kernel<<<grid_mfma, 256, 0, stream>>>(xb, T1, T2, T3, Wt, bias, out, N);
}

// Round 8
// 223.130 us; speedup vs baseline: 1.7098x; 1.0227x over previous
//
#include <hip/hip_runtime.h>

#define DIM 96
#define BCH 12          // bf16 chunks of 8 elems per node row
#define GBLK 192        // 16 nodes per block in gather
#define SCAN_CHUNK 1024

typedef __attribute__((ext_vector_type(8))) short bf16x8;
typedef __attribute__((ext_vector_type(4))) float f32x4;

__device__ __forceinline__ float bflo(unsigned u) { return __uint_as_float(u << 16); }
__device__ __forceinline__ float bfhi(unsigned u) { return __uint_as_float(u & 0xffff0000u); }
__device__ __forceinline__ unsigned f2bf(float f) {            // RNE f32 -> bf16 bits
    unsigned u = __float_as_uint(f);
    return (u + 0x7fffu + ((u >> 16) & 1u)) >> 16;
}
__device__ __forceinline__ unsigned packbf(float lo, float hi) {
    return (f2bf(lo) & 0xffffu) | (f2bf(hi) << 16);
}

// ---------------------------------------------------------------------------
__global__ void deg_kernel(const int* __restrict__ row, int E, int* __restrict__ degi) {
    int e = blockIdx.x * blockDim.x + threadIdx.x;
    if (e < E) atomicAdd(&degi[row[e]], 1);
}

// dinv = deg>0 ? 1/sqrt(deg) : 0 ; sdeg = sqrt(deg)
__global__ void dinv_kernel(const int* __restrict__ degi, float* __restrict__ dinv,
                            float* __restrict__ sdeg, int N) {
    int i = blockIdx.x * blockDim.x + threadIdx.x;
    if (i < N) {
        int d = degi[i];
        dinv[i] = (d > 0) ? rsqrtf((float)d) : 0.0f;
        sdeg[i] = sqrtf((float)d);
    }
}

// ---- multi-block exclusive scan of degi -> offsets ----
__global__ __launch_bounds__(256) void scan_blocks_kernel(
        const int* __restrict__ degi, int* __restrict__ offsets,
        int* __restrict__ blocksums, int N) {
    __shared__ int s[256];
    const int t = threadIdx.x;
    const int base = blockIdx.x * SCAN_CHUNK + t * 4;
    int v0 = 0, v1 = 0, v2 = 0, v3 = 0;
    if (base + 3 < N) {
        const int4 q = *reinterpret_cast<const int4*>(degi + base);
        v0 = q.x; v1 = q.y; v2 = q.z; v3 = q.w;
    } else {
        if (base + 0 < N) v0 = degi[base + 0];
        if (base + 1 < N) v1 = degi[base + 1];
        if (base + 2 < N) v2 = degi[base + 2];
        if (base + 3 < N) v3 = degi[base + 3];
    }
    const int mysum = v0 + v1 + v2 + v3;
    s[t] = mysum;
    __syncthreads();
    for (int off = 1; off < 256; off <<= 1) {
        int x = (t >= off) ? s[t - off] : 0;
        __syncthreads();
        s[t] += x;
        __syncthreads();
    }
    int run = s[t] - mysum;
    if (t == 255) blocksums[blockIdx.x] = s[255];
    if (base + 0 < N) offsets[base + 0] = run;  run += v0;
    if (base + 1 < N) offsets[base + 1] = run;  run += v1;
    if (base + 2 < N) offsets[base + 2] = run;  run += v2;
    if (base + 3 < N) offsets[base + 3] = run;
}

__global__ __launch_bounds__(256) void scan_sums_kernel(int* __restrict__ blocksums, int nb) {
    __shared__ int s[256];
    const int t = threadIdx.x;
    const int v = (t < nb) ? blocksums[t] : 0;
    s[t] = v;
    __syncthreads();
    for (int off = 1; off < 256; off <<= 1) {
        int x = (t >= off) ? s[t - off] : 0;
        __syncthreads();
        s[t] += x;
        __syncthreads();
    }
    if (t < nb) blocksums[t] = s[t] - v;
}

__global__ __launch_bounds__(256) void scan_add_kernel(
        int* __restrict__ offsets, const int* __restrict__ blocksums, int N, int E) {
    const int i = blockIdx.x * blockDim.x + threadIdx.x;
    if (i < N) offsets[i] += blocksums[i >> 10];  // SCAN_CHUNK == 1024
    if (i == 0) offsets[N] = E;
}

// place each edge into its row segment; payload is just the col index (4B)
__global__ void build_csr_kernel(const int* __restrict__ row, const int* __restrict__ col,
                                 const int* __restrict__ offsets,
                                 int* __restrict__ fill, int* __restrict__ colsorted, int E) {
    int e = blockIdx.x * blockDim.x + threadIdx.x;
    if (e >= E) return;
    int r = row[e];
    int p = offsets[r] + atomicAdd(&fill[r], 1);
    colsorted[p] = col[e];
}

// x (fp32) -> g0 = dinv[i]*x[i][:] in bf16 (NPAD rows, zero-padded)
__global__ __launch_bounds__(256) void cvt_x_kernel(const float* __restrict__ x,
        const float* __restrict__ dinv, ushort* __restrict__ xb, int N, int NPAD) {
    int i = blockIdx.x * blockDim.x + threadIdx.x;
    if (i >= NPAD * BCH) return;
    int g = i / BCH, c = i % BCH;
    uint4 o;
    if (g < N) {
        const float dv = dinv[g];
        const float4 f0 = *reinterpret_cast<const float4*>(x + (size_t)g * DIM + c * 8);
        const float4 f1 = *reinterpret_cast<const float4*>(x + (size_t)g * DIM + c * 8 + 4);
        o.x = packbf(dv * f0.x, dv * f0.y); o.y = packbf(dv * f0.z, dv * f0.w);
        o.z = packbf(dv * f1.x, dv * f1.y); o.w = packbf(dv * f1.z, dv * f1.w);
    } else {
        o = make_uint4(0u, 0u, 0u, 0u);
    }
    *reinterpret_cast<uint4*>(xb + (size_t)g * DIM + c * 8) = o;
}

// W [4][k][n] fp32 -> Wt [4][n][k] bf16 (k contiguous for MFMA B-fragments)
__global__ __launch_bounds__(256) void cvt_w_kernel(const float* __restrict__ w,
        ushort* __restrict__ wt) {
    int i = blockIdx.x * blockDim.x + threadIdx.x;
    if (i >= 4 * DIM * DIM) return;
    int m = i / (DIM * DIM), rem = i % (DIM * DIM);
    int n = rem / DIM, k = rem % DIM;
    wt[i] = (ushort)f2bf(w[m * DIM * DIM + k * DIM + n]);
}

// g-space hop: dst[i][:] = bf16( -scale*dinv[i]^2 * sum_e h[col[e]][:] (- prev[i][:]) )
// unit edge weights; bf16 rows, BCH chunks of 8; 4x unrolled independent gathers.
__global__ __launch_bounds__(GBLK) void gather_bf_kernel(
        const int* __restrict__ offsets, const int* __restrict__ colsorted,
        const float* __restrict__ dinv,
        const ushort* __restrict__ h, const ushort* __restrict__ prev,
        ushort* __restrict__ dst, int N, float scale) {
    int tid = blockIdx.x * blockDim.x + threadIdx.x;
    int node = tid / BCH;
    int c = tid % BCH;
    if (node >= N) return;
    int s = offsets[node];
    int e = offsets[node + 1];
    const ushort* hc = h + c * 8;

    float a[4][8];
#pragma unroll
    for (int u = 0; u < 4; ++u)
#pragma unroll
        for (int j = 0; j < 8; ++j) a[u][j] = 0.f;

    int k = s;
    for (; k + 3 < e; k += 4) {
        int c0 = colsorted[k + 0], c1 = colsorted[k + 1];
        int c2 = colsorted[k + 2], c3 = colsorted[k + 3];
        uint4 v[4];
        v[0] = *reinterpret_cast<const uint4*>(hc + (size_t)c0 * DIM);
        v[1] = *reinterpret_cast<const uint4*>(hc + (size_t)c1 * DIM);
        v[2] = *reinterpret_cast<const uint4*>(hc + (size_t)c2 * DIM);
        v[3] = *reinterpret_cast<const uint4*>(hc + (size_t)c3 * DIM);
#pragma unroll
        for (int u = 0; u < 4; ++u) {
            a[u][0] += bflo(v[u].x); a[u][1] += bfhi(v[u].x);
            a[u][2] += bflo(v[u].y); a[u][3] += bfhi(v[u].y);
            a[u][4] += bflo(v[u].z); a[u][5] += bfhi(v[u].z);
            a[u][6] += bflo(v[u].w); a[u][7] += bfhi(v[u].w);
        }
    }
    for (; k < e; ++k) {
        int c0 = colsorted[k];
        uint4 v0 = *reinterpret_cast<const uint4*>(hc + (size_t)c0 * DIM);
        a[0][0] += bflo(v0.x); a[0][1] += bfhi(v0.x);
        a[0][2] += bflo(v0.y); a[0][3] += bfhi(v0.y);
        a[0][4] += bflo(v0.z); a[0][5] += bfhi(v0.z);
        a[0][6] += bflo(v0.w); a[0][7] += bfhi(v0.w);
    }

    const float dv = dinv[node];
    const float m = -scale * dv * dv;       // -scale * D^{-1}
    float o[8];
#pragma unroll
    for (int j = 0; j < 8; ++j)
        o[j] = m * ((a[0][j] + a[1][j]) + (a[2][j] + a[3][j]));
    if (prev) {
        uint4 pv = *reinterpret_cast<const uint4*>(prev + (size_t)node * DIM + c * 8);
        o[0] -= bflo(pv.x); o[1] -= bfhi(pv.x);
        o[2] -= bflo(pv.y); o[3] -= bfhi(pv.y);
        o[4] -= bflo(pv.z); o[5] -= bfhi(pv.z);
        o[6] -= bflo(pv.w); o[7] -= bfhi(pv.w);
    }
    uint4 ov;
    ov.x = packbf(o[0], o[1]); ov.y = packbf(o[2], o[3]);
    ov.z = packbf(o[4], o[5]); ov.w = packbf(o[6], o[7]);
    *reinterpret_cast<uint4*>(dst + (size_t)node * DIM + c * 8) = ov;
}

// out[i][:] = sdeg[i] * (sum_m g_m @ W_m)[i][:] + bias  via mfma_f32_16x16x32_bf16
// 4 waves/block, 16 rows/wave, 6 col-tiles of 16; K=96 per matrix (3 steps of 32).
__global__ __launch_bounds__(256) void mfma_gemm_kernel(
        const ushort* __restrict__ A0, const ushort* __restrict__ A1,
        const ushort* __restrict__ A2, const ushort* __restrict__ A3,
        const ushort* __restrict__ Wt, const float* __restrict__ bias,
        const float* __restrict__ sdeg, float* __restrict__ out, int N) {
    const int wave = threadIdx.x >> 6;
    const int lane = threadIdx.x & 63;
    const int r  = lane & 15;    // A-row / B-col within tile
    const int kg = lane >> 4;    // k-group (8 elems each)
    const int row0 = blockIdx.x * 64 + wave * 16;
    const ushort* As[4] = {A0, A1, A2, A3};

    f32x4 acc[6];
#pragma unroll
    for (int n = 0; n < 6; ++n) acc[n] = (f32x4){0.f, 0.f, 0.f, 0.f};

#pragma unroll
    for (int m = 0; m < 4; ++m) {
        const ushort* Ap = As[m] + (size_t)(row0 + r) * DIM + kg * 8;
        const ushort* Wp = Wt + m * DIM * DIM + r * DIM + kg * 8;
#pragma unroll
        for (int ks = 0; ks < 3; ++ks) {
            bf16x8 af = *reinterpret_cast<const bf16x8*>(Ap + ks * 32);
#pragma unroll
            for (int n = 0; n < 6; ++n) {
                bf16x8 bfr = *reinterpret_cast<const bf16x8*>(Wp + n * 16 * DIM + ks * 32);
                acc[n] = __builtin_amdgcn_mfma_f32_16x16x32_bf16(af, bfr, acc[n], 0, 0, 0);
            }
        }
    }

    // C/D layout: col = lane&15, row = (lane>>4)*4 + reg
#pragma unroll
    for (int n = 0; n < 6; ++n) {
        const float bz = bias[n * 16 + r];
#pragma unroll
        for (int j = 0; j < 4; ++j) {
            int gr = row0 + kg * 4 + j;
            if (gr < N) out[(size_t)gr * DIM + n * 16 + r] = fmaf(sdeg[gr], acc[n][j], bz);
        }
    }
}

extern "C" void kernel_launch(void* const* d_in, const int* in_sizes, int n_in,
                              void* d_out, int out_size, void* d_ws, size_t ws_size,
                              hipStream_t stream) {
    const float* x    = (const float*)d_in[0];
    const int*   ei   = (const int*)d_in[1];
    const float* w    = (const float*)d_in[2];
    const float* bias = (const float*)d_in[3];
    float* out = (float*)d_out;

    const int N = in_sizes[0] / DIM;   // 50000
    const int E = in_sizes[1] / 2;     // 800000
    const int NPAD = (N + 63) & ~63;   // pad rows for 64-row MFMA blocks
    const int* row = ei;
    const int* col = ei + E;

    // ---- workspace layout ----
    char* p = (char*)d_ws;
    auto alloc = [&](size_t bytes) { char* q = p; p += (bytes + 15) & ~(size_t)15; return q; };
    int*    degi      = (int*)   alloc((size_t)N * 4);   // degree (adjacent to fill)
    int*    fill      = (int*)   alloc((size_t)N * 4);   // CSR fill counters
    int*    offsets   = (int*)   alloc((size_t)(N + 1) * 4);
    float*  dinv      = (float*) alloc((size_t)N * 4);
    float*  sdeg      = (float*) alloc((size_t)N * 4);
    int*    blocksums = (int*)   alloc(256 * 4);
    int*    colsorted = (int*)   alloc((size_t)E * 4);
    ushort* xb        = (ushort*)alloc((size_t)NPAD * DIM * 2);
    ushort* T1        = (ushort*)alloc((size_t)NPAD * DIM * 2);
    ushort* T2        = (ushort*)alloc((size_t)NPAD * DIM * 2);
    ushort* T3        = (ushort*)alloc((size_t)NPAD * DIM * 2);
    ushort* Wt        = (ushort*)alloc((size_t)4 * DIM * DIM * 2);

    const int BLK = 256;
    const int grid_edges  = (E + BLK - 1) / BLK;
    const int grid_nodes  = (N + BLK - 1) / BLK;
    const int grid_gather = (N * BCH + GBLK - 1) / GBLK;
    const int grid_cvtx   = (NPAD * BCH + BLK - 1) / BLK;
    const int grid_cvtw   = (4 * DIM * DIM + BLK - 1) / BLK;
    const int grid_mfma   = NPAD / 64;
    const int nscan       = (N + SCAN_CHUNK - 1) / SCAN_CHUNK;

    // ---- build CSR (unit weights; scaling folded into cvt_x / gather / epilogue) ----
    hipMemsetAsync(degi, 0, (size_t)2 * N * 4, stream);   // degi + fill in one shot
    deg_kernel<<<grid_edges, BLK, 0, stream>>>(row, E, degi);
    dinv_kernel<<<grid_nodes, BLK, 0, stream>>>(degi, dinv, sdeg, N);
    scan_blocks_kernel<<<nscan, 256, 0, stream>>>(degi, offsets, blocksums, N);
    scan_sums_kernel<<<1, 256, 0, stream>>>(blocksums, nscan);
    scan_add_kernel<<<grid_nodes, 256, 0, stream>>>(offsets, blocksums, N, E);
    build_csr_kernel<<<grid_edges, BLK, 0, stream>>>(row, col, offsets, fill, colsorted, E);

    // ---- bf16 conversions (g0 = dinv * x) ----
    cvt_x_kernel<<<grid_cvtx, BLK, 0, stream>>>(x, dinv, xb, N, NPAD);
    cvt_w_kernel<<<grid_cvtw, BLK, 0, stream>>>(w, Wt);

    // ---- g-space hops ----
    gather_bf_kernel<<<grid_gather, GBLK, 0, stream>>>(offsets, colsorted, dinv, xb, nullptr, T1, N, 1.0f);
    gather_bf_kernel<<<grid_gather, GBLK, 0, stream>>>(offsets, colsorted, dinv, T1, xb, T2, N, 2.0f);
    gather_bf_kernel<<<grid_gather, GBLK, 0, stream>>>(offsets, colsorted, dinv, T2, T1, T3, N, 2.0f);

    // ---- fused MFMA GEMM with sqrt(deg) row-scale in epilogue ----
    mfma_gemm_kernel<<<grid_mfma, 256, 0, stream>>>(xb, T1, T2, T3, Wt, bias, sdeg, out, N);
}

// Round 9
// 180.835 us; speedup vs baseline: 2.1097x; 1.2339x over previous
//
#include <hip/hip_runtime.h>

#define DIM 96
#define BCH 12          // bf16 chunks of 8 elems per node row
#define GBLK 192        // 16 nodes per block in gather
#define BROWS 128       // rows per bucket
#define MAXB 1024       // max buckets supported (N <= 131072)
#define EPB 8192        // edges per block in binning

typedef __attribute__((ext_vector_type(8))) short bf16x8;
typedef __attribute__((ext_vector_type(4))) float f32x4;

__device__ __forceinline__ float bflo(unsigned u) { return __uint_as_float(u << 16); }
__device__ __forceinline__ float bfhi(unsigned u) { return __uint_as_float(u & 0xffff0000u); }
__device__ __forceinline__ unsigned f2bf(float f) {            // RNE f32 -> bf16 bits
    unsigned u = __float_as_uint(f);
    return (u + 0x7fffu + ((u >> 16) & 1u)) >> 16;
}
__device__ __forceinline__ unsigned packbf(float lo, float hi) {
    return (f2bf(lo) & 0xffffu) | (f2bf(hi) << 16);
}

// ---------------------------------------------------------------------------
// pass 1: per-block LDS histogram of row>>7 -> global bucket_cnt
__global__ __launch_bounds__(256) void bin_count_kernel(
        const int* __restrict__ row, int E, int* __restrict__ bucket_cnt, int NB) {
    __shared__ int cnt[MAXB];
    const int t = threadIdx.x;
    for (int b = t; b < MAXB; b += 256) cnt[b] = 0;
    __syncthreads();
    const int base = blockIdx.x * EPB;
    const int end = min(base + EPB, E);
    for (int e = base + t; e < end; e += 256)
        atomicAdd(&cnt[row[e] >> 7], 1);
    __syncthreads();
    for (int b = t; b < NB; b += 256)
        if (cnt[b]) atomicAdd(&bucket_cnt[b], cnt[b]);
}

// pass 2: single block exclusive-scan of bucket_cnt -> bucket_off, bucket_fill
__global__ __launch_bounds__(512) void bin_scan_kernel(
        const int* __restrict__ bucket_cnt, int* __restrict__ bucket_off,
        int* __restrict__ bucket_fill, int* __restrict__ offsets, int NB, int N, int E) {
    __shared__ int s[512];
    const int t = threadIdx.x;
    const int v = (t < NB) ? bucket_cnt[t] : 0;
    s[t] = v;
    __syncthreads();
    for (int off = 1; off < 512; off <<= 1) {
        int x = (t >= off) ? s[t - off] : 0;
        __syncthreads();
        s[t] += x;
        __syncthreads();
    }
    if (t < NB) {
        int excl = s[t] - v;
        bucket_off[t] = excl;
        bucket_fill[t] = excl;
    }
    if (t == 0) {
        bucket_off[NB] = E;
        offsets[N] = E;
    }
}

// pass 3: bin edges into bucket segments; payload packed (rw<<17)|col (4B)
__global__ __launch_bounds__(256) void bin_place_kernel(
        const int* __restrict__ row, const int* __restrict__ col, int E,
        int* __restrict__ bucket_fill, int* __restrict__ binned, int NB) {
    __shared__ int cnt[MAXB];
    __shared__ int base[MAXB];
    const int t = threadIdx.x;
    for (int b = t; b < MAXB; b += 256) cnt[b] = 0;
    __syncthreads();
    const int bs = blockIdx.x * EPB;
    const int end = min(bs + EPB, E);
    for (int e = bs + t; e < end; e += 256)
        atomicAdd(&cnt[row[e] >> 7], 1);
    __syncthreads();
    for (int b = t; b < NB; b += 256)
        if (cnt[b]) base[b] = atomicAdd(&bucket_fill[b], cnt[b]);
    __syncthreads();
    for (int b = t; b < MAXB; b += 256) cnt[b] = 0;
    __syncthreads();
    for (int e = bs + t; e < end; e += 256) {
        int r = row[e];
        int b = r >> 7;
        int pos = base[b] + atomicAdd(&cnt[b], 1);
        binned[pos] = ((r & (BROWS - 1)) << 17) | col[e];
    }
}

// pass 4: one block per bucket: local histogram+scan -> deg/dinv/sdeg/offsets,
// then local scatter of cols into CSR order (writes stay in an L2-hot window)
__global__ __launch_bounds__(256) void bucket_build_kernel(
        const int* __restrict__ bucket_off, const int* __restrict__ binned,
        float* __restrict__ dinv, float* __restrict__ sdeg,
        int* __restrict__ offsets, int* __restrict__ colsorted, int N) {
    __shared__ int cnt[BROWS];
    __shared__ int sc[BROWS];
    __shared__ int fill[BROWS];
    const int t = threadIdx.x;
    const int b = blockIdx.x;
    const int s = bucket_off[b];
    const int e2 = bucket_off[b + 1];
    if (t < BROWS) cnt[t] = 0;
    __syncthreads();
    for (int k = s + t; k < e2; k += 256)
        atomicAdd(&cnt[binned[k] >> 17], 1);
    __syncthreads();
    if (t < BROWS) sc[t] = cnt[t];
    __syncthreads();
    for (int off = 1; off < BROWS; off <<= 1) {
        int x = (t < BROWS && t >= off) ? sc[t - off] : 0;
        __syncthreads();
        if (t < BROWS) sc[t] += x;
        __syncthreads();
    }
    if (t < BROWS) {
        int excl = sc[t] - cnt[t];
        int node = b * BROWS + t;
        if (node < N) {
            int d = cnt[t];
            dinv[node] = (d > 0) ? rsqrtf((float)d) : 0.0f;
            sdeg[node] = sqrtf((float)d);
            offsets[node] = s + excl;
        }
        fill[t] = s + excl;
    }
    __syncthreads();
    for (int k = s + t; k < e2; k += 256) {
        int v = binned[k];
        int p = atomicAdd(&fill[v >> 17], 1);
        colsorted[p] = v & 0x1FFFF;
    }
}

// x (fp32) -> g0 = dinv[i]*x[i][:] in bf16 (NPAD rows, zero-padded)
__global__ __launch_bounds__(256) void cvt_x_kernel(const float* __restrict__ x,
        const float* __restrict__ dinv, ushort* __restrict__ xb, int N, int NPAD) {
    int i = blockIdx.x * blockDim.x + threadIdx.x;
    if (i >= NPAD * BCH) return;
    int g = i / BCH, c = i % BCH;
    uint4 o;
    if (g < N) {
        const float dv = dinv[g];
        const float4 f0 = *reinterpret_cast<const float4*>(x + (size_t)g * DIM + c * 8);
        const float4 f1 = *reinterpret_cast<const float4*>(x + (size_t)g * DIM + c * 8 + 4);
        o.x = packbf(dv * f0.x, dv * f0.y); o.y = packbf(dv * f0.z, dv * f0.w);
        o.z = packbf(dv * f1.x, dv * f1.y); o.w = packbf(dv * f1.z, dv * f1.w);
    } else {
        o = make_uint4(0u, 0u, 0u, 0u);
    }
    *reinterpret_cast<uint4*>(xb + (size_t)g * DIM + c * 8) = o;
}

// W [4][k][n] fp32 -> Wt [4][n][k] bf16 (k contiguous for MFMA B-fragments)
__global__ __launch_bounds__(256) void cvt_w_kernel(const float* __restrict__ w,
        ushort* __restrict__ wt) {
    int i = blockIdx.x * blockDim.x + threadIdx.x;
    if (i >= 4 * DIM * DIM) return;
    int m = i / (DIM * DIM), rem = i % (DIM * DIM);
    int n = rem / DIM, k = rem % DIM;
    wt[i] = (ushort)f2bf(w[m * DIM * DIM + k * DIM + n]);
}

// g-space hop: dst[i][:] = bf16( -scale*dinv[i]^2 * sum_e h[col[e]][:] (- prev[i][:]) )
__global__ __launch_bounds__(GBLK) void gather_bf_kernel(
        const int* __restrict__ offsets, const int* __restrict__ colsorted,
        const float* __restrict__ dinv,
        const ushort* __restrict__ h, const ushort* __restrict__ prev,
        ushort* __restrict__ dst, int N, float scale) {
    int tid = blockIdx.x * blockDim.x + threadIdx.x;
    int node = tid / BCH;
    int c = tid % BCH;
    if (node >= N) return;
    int s = offsets[node];
    int e = offsets[node + 1];
    const ushort* hc = h + c * 8;

    float a[4][8];
#pragma unroll
    for (int u = 0; u < 4; ++u)
#pragma unroll
        for (int j = 0; j < 8; ++j) a[u][j] = 0.f;

    int k = s;
    for (; k + 3 < e; k += 4) {
        int c0 = colsorted[k + 0], c1 = colsorted[k + 1];
        int c2 = colsorted[k + 2], c3 = colsorted[k + 3];
        uint4 v[4];
        v[0] = *reinterpret_cast<const uint4*>(hc + (size_t)c0 * DIM);
        v[1] = *reinterpret_cast<const uint4*>(hc + (size_t)c1 * DIM);
        v[2] = *reinterpret_cast<const uint4*>(hc + (size_t)c2 * DIM);
        v[3] = *reinterpret_cast<const uint4*>(hc + (size_t)c3 * DIM);
#pragma unroll
        for (int u = 0; u < 4; ++u) {
            a[u][0] += bflo(v[u].x); a[u][1] += bfhi(v[u].x);
            a[u][2] += bflo(v[u].y); a[u][3] += bfhi(v[u].y);
            a[u][4] += bflo(v[u].z); a[u][5] += bfhi(v[u].z);
            a[u][6] += bflo(v[u].w); a[u][7] += bfhi(v[u].w);
        }
    }
    for (; k < e; ++k) {
        int c0 = colsorted[k];
        uint4 v0 = *reinterpret_cast<const uint4*>(hc + (size_t)c0 * DIM);
        a[0][0] += bflo(v0.x); a[0][1] += bfhi(v0.x);
        a[0][2] += bflo(v0.y); a[0][3] += bfhi(v0.y);
        a[0][4] += bflo(v0.z); a[0][5] += bfhi(v0.z);
        a[0][6] += bflo(v0.w); a[0][7] += bfhi(v0.w);
    }

    const float dv = dinv[node];
    const float m = -scale * dv * dv;       // -scale * D^{-1}
    float o[8];
#pragma unroll
    for (int j = 0; j < 8; ++j)
        o[j] = m * ((a[0][j] + a[1][j]) + (a[2][j] + a[3][j]));
    if (prev) {
        uint4 pv = *reinterpret_cast<const uint4*>(prev + (size_t)node * DIM + c * 8);
        o[0] -= bflo(pv.x); o[1] -= bfhi(pv.x);
        o[2] -= bflo(pv.y); o[3] -= bfhi(pv.y);
        o[4] -= bflo(pv.z); o[5] -= bfhi(pv.z);
        o[6] -= bflo(pv.w); o[7] -= bfhi(pv.w);
    }
    uint4 ov;
    ov.x = packbf(o[0], o[1]); ov.y = packbf(o[2], o[3]);
    ov.z = packbf(o[4], o[5]); ov.w = packbf(o[6], o[7]);
    *reinterpret_cast<uint4*>(dst + (size_t)node * DIM + c * 8) = ov;
}

// out[i][:] = sdeg[i] * (sum_m g_m @ W_m)[i][:] + bias  via mfma_f32_16x16x32_bf16
__global__ __launch_bounds__(256) void mfma_gemm_kernel(
        const ushort* __restrict__ A0, const ushort* __restrict__ A1,
        const ushort* __restrict__ A2, const ushort* __restrict__ A3,
        const ushort* __restrict__ Wt, const float* __restrict__ bias,
        const float* __restrict__ sdeg, float* __restrict__ out, int N) {
    const int wave = threadIdx.x >> 6;
    const int lane = threadIdx.x & 63;
    const int r  = lane & 15;    // A-row / B-col within tile
    const int kg = lane >> 4;    // k-group (8 elems each)
    const int row0 = blockIdx.x * 64 + wave * 16;
    const ushort* As[4] = {A0, A1, A2, A3};

    f32x4 acc[6];
#pragma unroll
    for (int n = 0; n < 6; ++n) acc[n] = (f32x4){0.f, 0.f, 0.f, 0.f};

#pragma unroll
    for (int m = 0; m < 4; ++m) {
        const ushort* Ap = As[m] + (size_t)(row0 + r) * DIM + kg * 8;
        const ushort* Wp = Wt + m * DIM * DIM + r * DIM + kg * 8;
#pragma unroll
        for (int ks = 0; ks < 3; ++ks) {
            bf16x8 af = *reinterpret_cast<const bf16x8*>(Ap + ks * 32);
#pragma unroll
            for (int n = 0; n < 6; ++n) {
                bf16x8 bfr = *reinterpret_cast<const bf16x8*>(Wp + n * 16 * DIM + ks * 32);
                acc[n] = __builtin_amdgcn_mfma_f32_16x16x32_bf16(af, bfr, acc[n], 0, 0, 0);
            }
        }
    }

    // C/D layout: col = lane&15, row = (lane>>4)*4 + reg
#pragma unroll
    for (int n = 0; n < 6; ++n) {
        const float bz = bias[n * 16 + r];
#pragma unroll
        for (int j = 0; j < 4; ++j) {
            int gr = row0 + kg * 4 + j;
            if (gr < N) out[(size_t)gr * DIM + n * 16 + r] = fmaf(sdeg[gr], acc[n][j], bz);
        }
    }
}

extern "C" void kernel_launch(void* const* d_in, const int* in_sizes, int n_in,
                              void* d_out, int out_size, void* d_ws, size_t ws_size,
                              hipStream_t stream) {
    const float* x    = (const float*)d_in[0];
    const int*   ei   = (const int*)d_in[1];
    const float* w    = (const float*)d_in[2];
    const float* bias = (const float*)d_in[3];
    float* out = (float*)d_out;

    const int N = in_sizes[0] / DIM;   // 50000
    const int E = in_sizes[1] / 2;     // 800000
    const int NPAD = (N + 63) & ~63;   // pad rows for 64-row MFMA blocks
    const int NB = (N + BROWS - 1) / BROWS;  // 391 buckets
    const int* row = ei;
    const int* col = ei + E;

    // ---- workspace layout ----
    char* p = (char*)d_ws;
    auto alloc = [&](size_t bytes) { char* q = p; p += (bytes + 15) & ~(size_t)15; return q; };
    int*    bucket_cnt  = (int*)   alloc((size_t)NB * 4);
    int*    bucket_off  = (int*)   alloc((size_t)(NB + 1) * 4);
    int*    bucket_fill = (int*)   alloc((size_t)NB * 4);
    int*    offsets     = (int*)   alloc((size_t)(N + 1) * 4);
    float*  dinv        = (float*) alloc((size_t)N * 4);
    float*  sdeg        = (float*) alloc((size_t)N * 4);
    int*    binned      = (int*)   alloc((size_t)E * 4);
    int*    colsorted   = (int*)   alloc((size_t)E * 4);
    ushort* xb          = (ushort*)alloc((size_t)NPAD * DIM * 2);
    ushort* T1          = (ushort*)alloc((size_t)NPAD * DIM * 2);
    ushort* T2          = (ushort*)alloc((size_t)NPAD * DIM * 2);
    ushort* T3          = (ushort*)alloc((size_t)NPAD * DIM * 2);
    ushort* Wt          = (ushort*)alloc((size_t)4 * DIM * DIM * 2);

    const int BLK = 256;
    const int grid_bin    = (E + EPB - 1) / EPB;           // 98
    const int grid_gather = (N * BCH + GBLK - 1) / GBLK;
    const int grid_cvtx   = (NPAD * BCH + BLK - 1) / BLK;
    const int grid_cvtw   = (4 * DIM * DIM + BLK - 1) / BLK;
    const int grid_mfma   = NPAD / 64;

    // ---- bucketed CSR build ----
    hipMemsetAsync(bucket_cnt, 0, (size_t)NB * 4, stream);
    bin_count_kernel<<<grid_bin, 256, 0, stream>>>(row, E, bucket_cnt, NB);
    bin_scan_kernel<<<1, 512, 0, stream>>>(bucket_cnt, bucket_off, bucket_fill,
                                           offsets, NB, N, E);
    bin_place_kernel<<<grid_bin, 256, 0, stream>>>(row, col, E, bucket_fill, binned, NB);
    bucket_build_kernel<<<NB, 256, 0, stream>>>(bucket_off, binned, dinv, sdeg,
                                                offsets, colsorted, N);

    // ---- bf16 conversions (g0 = dinv * x) ----
    cvt_x_kernel<<<grid_cvtx, BLK, 0, stream>>>(x, dinv, xb, N, NPAD);
    cvt_w_kernel<<<grid_cvtw, BLK, 0, stream>>>(w, Wt);

    // ---- g-space hops ----
    gather_bf_kernel<<<grid_gather, GBLK, 0, stream>>>(offsets, colsorted, dinv, xb, nullptr, T1, N, 1.0f);
    gather_bf_kernel<<<grid_gather, GBLK, 0, stream>>>(offsets, colsorted, dinv, T1, xb, T2, N, 2.0f);
    gather_bf_kernel<<<grid_gather, GBLK, 0, stream>>>(offsets, colsorted, dinv, T2, T1, T3, N, 2.0f);

    // ---- fused MFMA GEMM with sqrt(deg) row-scale in epilogue ----
    mfma_gemm_kernel<<<grid_mfma, 256, 0, stream>>>(xb, T1, T2, T3, Wt, bias, sdeg, out, N);
}